// Round 3
// baseline (58.301 us; speedup 1.0000x reference)
//
#include <hip/hip_runtime.h>
#include <hip/hip_bf16.h>
#include <math.h>

#define NN 4096
#define INDIM 45
#define HH 44
#define NHEAD 4
#define HD 11
#define NEDGE 131072
#define CAP 512            // max allowed columns per row (Poisson(32); P(>CAP) ~ 0)
#define MASKW (NN / 64)
#define NPB 32             // nodes per block in proj_fused

__device__ __forceinline__ float wsum64(float v) {
    #pragma unroll
    for (int i = 32; i > 0; i >>= 1) v += __shfl_xor(v, i, 64);
    return v;
}
__device__ __forceinline__ float wmax64(float v) {
    #pragma unroll
    for (int i = 32; i > 0; i >>= 1) v = fmaxf(v, __shfl_xor(v, i, 64));
    return v;
}

// ---------------- Kernel 1: fused input + QKV projection ----------------
// Block handles NPB nodes: phase A computes x into LDS, phase B emits Q/K/V [N][44].
__global__ __launch_bounds__(256)
void proj_fused(const float* __restrict__ nf,
                const float* __restrict__ Wp, const float* __restrict__ bp,
                const float* __restrict__ Wq, const float* __restrict__ bq,
                const float* __restrict__ Wk, const float* __restrict__ bk,
                const float* __restrict__ Wv, const float* __restrict__ bv,
                float* __restrict__ Qs, float* __restrict__ Ks, float* __restrict__ Vs) {
    __shared__ float xs[NPB][HH];
    const int n0 = blockIdx.x * NPB;
    for (int idx = threadIdx.x; idx < NPB * HH; idx += 256) {
        int nl = idx / HH, j = idx % HH;
        const float* row = nf + (size_t)(n0 + nl) * INDIM;
        float a = bp[j];
        #pragma unroll
        for (int k = 0; k < INDIM; ++k) a += row[k] * Wp[k * HH + j];
        xs[nl][j] = a;
    }
    __syncthreads();
    for (int idx = threadIdx.x; idx < NPB * HH; idx += 256) {
        int nl = idx / HH, j = idx % HH;
        const float* row = xs[nl];
        float aq = bq[j], ak = bk[j], av = bv[j];
        #pragma unroll
        for (int k = 0; k < HH; ++k) {
            float xv = row[k];
            aq += xv * Wq[k * HH + j];
            ak += xv * Wk[k * HH + j];
            av += xv * Wv[k * HH + j];
        }
        size_t o = (size_t)(n0 + nl) * HH + j;
        Qs[o] = aq; Ks[o] = ak; Vs[o] = av;
    }
}

// ---------------- Kernel 2: bitmask of ALLOWED pairs (edges + diagonal) ----------------
__global__ __launch_bounds__(256)
void build_mask(const int* __restrict__ ei, unsigned long long* __restrict__ mask) {
    int i = blockIdx.x * blockDim.x + threadIdx.x;
    if (i < NEDGE) {
        int r = ei[i];          // query
        int c = ei[NEDGE + i];  // key
        atomicOr(&mask[(size_t)r * MASKW + (c >> 6)], 1ull << (c & 63));
    }
    if (i < NN) {
        atomicOr(&mask[(size_t)i * MASKW + (i >> 6)], 1ull << (i & 63));
    }
}

// ---------------- Kernel 3: sparse attention (all 4 heads per wave) + out proj ----------------
// Block = 256 = 4 waves = 4 query rows. Each wave: compact its mask row into LDS
// (wave prefix scan, deterministic sorted order), then online softmax over allowed
// columns for all 4 heads at once (temporal gather + sqrt shared across heads),
// butterfly merge, fused @ Wo + bo.
__global__ __launch_bounds__(256)
void attn_fused(const float* __restrict__ Qs, const float* __restrict__ Ks,
                const float* __restrict__ Vs, const float* __restrict__ temporal,
                const unsigned long long* __restrict__ mask,
                const float* __restrict__ Wo, const float* __restrict__ bo,
                float* __restrict__ out) {
    const int lane = threadIdx.x & 63;
    const int r = threadIdx.x >> 6;           // local row (= wave id)
    const int n = blockIdx.x * 4 + r;
    const float scale = 0.30151134457776363f; // 1/sqrt(11)
    const float tbmul = 9.99990000099999f;    // 1/(0.1+1e-6)

    __shared__ int cols_s[4][CAP];
    __shared__ float att_s[4][HH];

    // --- compact mask row into LDS (sorted, deterministic) ---
    unsigned long long w = mask[(size_t)n * MASKW + lane];
    int c = __popcll(w);
    int inc = c;
    #pragma unroll
    for (int i = 1; i < 64; i <<= 1) {
        int v = __shfl_up(inc, i, 64);
        if (lane >= i) inc += v;
    }
    int off = inc - c;                 // exclusive prefix
    int deg = __shfl(inc, 63, 64);
    if (deg > CAP) deg = CAP;
    while (w) {
        int b = __builtin_ctzll(w);
        w &= w - 1;
        if (off < CAP) cols_s[r][off] = lane * 64 + b;
        ++off;
    }
    __syncthreads();

    // --- per-head state ---
    float q[NHEAD][HD];
    const float* qp = Qs + (size_t)n * HH;
    #pragma unroll
    for (int h = 0; h < NHEAD; ++h)
        #pragma unroll
        for (int d = 0; d < HD; ++d) q[h][d] = qp[h * HD + d];

    float mcur[NHEAD], lsum[NHEAD], oacc[NHEAD][HD];
    #pragma unroll
    for (int h = 0; h < NHEAD; ++h) {
        mcur[h] = -INFINITY; lsum[h] = 0.f;
        #pragma unroll
        for (int d = 0; d < HD; ++d) oacc[h][d] = 0.f;
    }

    for (int base = 0; base < deg; base += 64) {
        const int j = base + lane;
        const bool act = j < deg;
        const int col = act ? cols_s[r][j] : 0;
        float t = temporal[((size_t)n * NN + col) * 2];   // the one HBM gather
        const float* kp = Ks + (size_t)col * HH;
        const float* vp = Vs + (size_t)col * HH;
        float tb = sqrtf(t * tbmul);
        #pragma unroll
        for (int h = 0; h < NHEAD; ++h) {
            float s = 0.f;
            #pragma unroll
            for (int d = 0; d < HD; ++d) s += q[h][d] * kp[h * HD + d];
            s = s * scale - tb;
            if (act) {
                if (s > mcur[h]) {
                    float f = __expf(mcur[h] - s);
                    lsum[h] *= f;
                    #pragma unroll
                    for (int d = 0; d < HD; ++d) oacc[h][d] *= f;
                    mcur[h] = s;
                }
                float p = __expf(s - mcur[h]);
                lsum[h] += p;
                #pragma unroll
                for (int d = 0; d < HD; ++d) oacc[h][d] += p * vp[h * HD + d];
            }
        }
    }

    // --- exact log-sum-exp merge across the wave ---
    #pragma unroll
    for (int h = 0; h < NHEAD; ++h) {
        float M = wmax64(mcur[h]);
        float sc = (mcur[h] == -INFINITY) ? 0.f : __expf(mcur[h] - M);
        float L = wsum64(lsum[h] * sc);
        float inv = 1.f / L;
        #pragma unroll
        for (int d = 0; d < HD; ++d) {
            float o = wsum64(oacc[h][d] * sc);
            if (lane == d) att_s[r][h * HD + d] = o * inv;
        }
    }
    __syncthreads();

    // --- fused output projection ---
    int tid = threadIdx.x;
    if (tid < 4 * HH) {
        int rr = tid / HH, j = tid % HH;
        float a = bo[j];
        #pragma unroll
        for (int k = 0; k < HH; ++k) a += att_s[rr][k] * Wo[k * HH + j];
        out[(size_t)(blockIdx.x * 4 + rr) * HH + j] = a;
    }
}

extern "C" void kernel_launch(void* const* d_in, const int* in_sizes, int n_in,
                              void* d_out, int out_size, void* d_ws, size_t ws_size,
                              hipStream_t stream) {
    const float* nf       = (const float*)d_in[0];
    const int*   ei       = (const int*)d_in[1];
    const float* temporal = (const float*)d_in[2];
    const float* Wp = (const float*)d_in[3];
    const float* bp = (const float*)d_in[4];
    const float* Wq = (const float*)d_in[5];
    const float* bq = (const float*)d_in[6];
    const float* Wk = (const float*)d_in[7];
    const float* bk = (const float*)d_in[8];
    const float* Wv = (const float*)d_in[9];
    const float* bv = (const float*)d_in[10];
    const float* Wo = (const float*)d_in[11];
    const float* bo = (const float*)d_in[12];
    float* out = (float*)d_out;

    char* ws = (char*)d_ws;
    unsigned long long* mask = (unsigned long long*)ws;        // 2 MB
    float* Qs = (float*)(ws + (2u << 20));
    float* Ks = Qs + NN * HH;
    float* Vs = Ks + NN * HH;

    hipMemsetAsync(mask, 0, NN * MASKW * sizeof(unsigned long long), stream);
    proj_fused<<<NN / NPB, 256, 0, stream>>>(nf, Wp, bp, Wq, bq, Wk, bk, Wv, bv, Qs, Ks, Vs);
    build_mask<<<(NEDGE + 255) / 256, 256, 0, stream>>>(ei, mask);
    attn_fused<<<NN / 4, 256, 0, stream>>>(Qs, Ks, Vs, temporal, mask, Wo, bo, out);
}